// Round 19
// baseline (251.909 us; speedup 1.0000x reference)
//
#include <hip/hip_runtime.h>
#include <hip/hip_bf16.h>
#include <hip/hip_fp16.h>
#include <math.h>

#define NN 50000
#define NE 800000
#define C  128
#define NR 8            // dst ranges (XCD-affine via blockIdx%8 heuristic)
#define RNG (NN / NR)
#define GCH 1568        // ((NE+4095)/4096)*NR
typedef unsigned int u32;
typedef unsigned short u16;

using f32x4  = __attribute__((ext_vector_type(4))) float;
using half8  = __attribute__((ext_vector_type(8))) _Float16;
using half2v = __attribute__((ext_vector_type(2))) _Float16;

__device__ __forceinline__ u16 f2h(float f) {
    _Float16 h = (_Float16)f;
    return __builtin_bit_cast(u16, h);
}

__device__ __forceinline__ void gload_lds16(const u16* g, u16* l) {
    __builtin_amdgcn_global_load_lds(
        (const __attribute__((address_space(1))) u32*)g,
        (__attribute__((address_space(3))) u32*)l,
        16, 0, 0);
}

// ---------------- CSR build ----------------

__global__ __launch_bounds__(1024) void k_zero(int* __restrict__ p, int n) {
    int i = blockIdx.x * 1024 + threadIdx.x;
    if (i < n) p[i] = 0;
}

// merged: histogram (blocks 0..GCH-1) + weight pack (next 640) + x convert (rest)
struct PackArgs {
    const float* Wl[5]; const float* Wr[5];
    u16* Wh[5];
};
__global__ void k_preph(PackArgs pa, const float* __restrict__ x, u32* __restrict__ oh,
                        const int* __restrict__ dst, int* __restrict__ deg, int n64, int nE) {
    int bid = blockIdx.x;
    if (bid < GCH) {                       // range-partitioned histogram
        int r    = bid & (NR - 1);
        int base = (bid >> 3) * 4096;
        int lo   = r * RNG, hi = lo + RNG;
        #pragma unroll
        for (int it = 0; it < 16; ++it) {
            int e = base + it * 256 + threadIdx.x;
            if (e < nE) {
                int d = dst[e];
                if (d >= lo && d < hi) atomicAdd(&deg[d], 1);
            }
        }
    } else if (bid < GCH + 640) {          // weight pack (5 layers x 128 blocks)
        int b   = bid - GCH;
        int L   = b >> 7;
        int idx = (b & 127) * 256 + threadIdx.x;
        int j = idx & 7, l = (idx >> 3) & 63, s = (idx >> 9) & 7, t = idx >> 12;
        int nrow = t * 16 + (l & 15);
        int k    = s * 32 + (l >> 4) * 8 + j;
        float v  = (k < 128) ? pa.Wl[L][nrow * 128 + k] : pa.Wr[L][nrow * 128 + (k - 128)];
        pa.Wh[L][idx] = f2h(v);
    } else {                               // x conversion
        int i = (bid - GCH - 640) * 256 + threadIdx.x;
        if (i < n64) {
            float2 v = *(const float2*)(x + (size_t)i * 2);
            oh[i] = ((u32)f2h(v.x)) | (((u32)f2h(v.y)) << 16);
        }
    }
}

__global__ __launch_bounds__(1024) void k_scan_blk(const int* __restrict__ deg, int* __restrict__ rowptr,
                                                   int* __restrict__ bsum, int n) {
    __shared__ int wsum[16];
    int tid = threadIdx.x, lane = tid & 63, wid = tid >> 6;
    int i = blockIdx.x * 1024 + tid;
    int v = (i < n) ? deg[i] : 0;
    int incl = v;
    #pragma unroll
    for (int d = 1; d < 64; d <<= 1) {
        int t = __shfl_up(incl, d, 64);
        if (lane >= d) incl += t;
    }
    if (lane == 63) wsum[wid] = incl;
    __syncthreads();
    int wo = 0;
    #pragma unroll
    for (int w = 0; w < 16; ++w) wo += (w < wid) ? wsum[w] : 0;
    if (i < n) rowptr[i + 1] = wo + incl;
    if (tid == 1023) bsum[blockIdx.x] = wo + incl;
}

// scan bsum in-register per block (nb <= 49 < 64), then add offsets
__global__ __launch_bounds__(1024) void k_scan_add(int* __restrict__ rowptr, const int* __restrict__ bsum,
                                                   int n, int nb) {
    __shared__ int soff;
    int tid = threadIdx.x;
    if (tid < 64) {
        int v = (tid < nb) ? bsum[tid] : 0;
        int incl = v;
        #pragma unroll
        for (int d = 1; d < 64; d <<= 1) {
            int t = __shfl_up(incl, d, 64);
            if (tid >= d) incl += t;
        }
        if (tid == blockIdx.x) soff = incl - v;   // exclusive prefix for this block
    }
    __syncthreads();
    int i = blockIdx.x * 1024 + tid;
    if (i == 0) rowptr[0] = 0;
    if (i < n) rowptr[i + 1] += soff;
}

__global__ __launch_bounds__(256) void k_fill_x(const int* __restrict__ src, const int* __restrict__ dst,
                                                const int* __restrict__ rowptr, int* __restrict__ deg,
                                                u16* __restrict__ esrc, int nE) {
    int r    = blockIdx.x & (NR - 1);
    int base = (blockIdx.x >> 3) * 4096;
    int lo   = r * RNG, hi = lo + RNG;
    #pragma unroll
    for (int it = 0; it < 16; ++it) {
        int e = base + it * 256 + threadIdx.x;
        if (e < nE) {
            int d = dst[e];
            if (d >= lo && d < hi) {
                int old = atomicSub(&deg[d], 1);
                esrc[rowptr[d + 1] - old] = (u16)src[e];
            }
        }
    }
}

// ---------------- segment max over packed fp16, 2 nodes per wave ----------------
// Each wave owns two nodes; both 16-load batches are issued before either
// reduce -> 32 independent gathers in flight (latency hiding). Bounds are
// wave-uniform (readfirstlane) -> scalar index loads, no divergence.
__device__ __forceinline__ void seg2_body(const u32* __restrict__ h2, const int* __restrict__ rowptr,
                                          const u16* __restrict__ esrc, u32* __restrict__ agg2,
                                          int node0, int node1, int lane, int n) {
    int beg0 = 0, end0 = 0, beg1 = 0, end1 = 0;
    if (node0 < n) {
        beg0 = __builtin_amdgcn_readfirstlane(rowptr[node0]);
        end0 = __builtin_amdgcn_readfirstlane(rowptr[node0 + 1]);
    }
    if (node1 < n) {
        beg1 = __builtin_amdgcn_readfirstlane(rowptr[node1]);
        end1 = __builtin_amdgcn_readfirstlane(rowptr[node1 + 1]);
    }
    _Float16 ninf = (_Float16)(-INFINITY);
    half2v m0 = {ninf, ninf}, m1 = {ninf, ninf};
    int i0 = beg0, i1 = beg1;
    int last0 = end0 - 1, last1 = end1 - 1;
    while ((i0 < end0) || (i1 < end1)) {
        u32 w0[16], w1[16];
        bool a0 = i0 < end0, a1 = i1 < end1;
        if (a0) {
            #pragma unroll
            for (int q = 0; q < 16; ++q) {
                int e = i0 + q; if (e > last0) e = last0;
                w0[q] = h2[((size_t)esrc[e] << 6) + lane];
            }
        }
        if (a1) {
            #pragma unroll
            for (int q = 0; q < 16; ++q) {
                int e = i1 + q; if (e > last1) e = last1;
                w1[q] = h2[((size_t)esrc[e] << 6) + lane];
            }
        }
        if (a0) {
            #pragma unroll
            for (int q = 0; q < 16; ++q)
                m0 = __builtin_elementwise_max(m0, __builtin_bit_cast(half2v, w0[q]));
            i0 += 16;
        }
        if (a1) {
            #pragma unroll
            for (int q = 0; q < 16; ++q)
                m1 = __builtin_elementwise_max(m1, __builtin_bit_cast(half2v, w1[q]));
            i1 += 16;
        }
    }
    if (node0 < n) {
        u32 r = (end0 > beg0) ? __builtin_bit_cast(u32, m0) : 0u;
        __builtin_nontemporal_store(r, &agg2[(size_t)node0 * 64 + lane]);
    }
    if (node1 < n) {
        u32 r = (end1 > beg1) ? __builtin_bit_cast(u32, m1) : 0u;
        __builtin_nontemporal_store(r, &agg2[(size_t)node1 * 64 + lane]);
    }
}

// single plane: block = 4 waves = 8 nodes
__global__ __launch_bounds__(256) void k_segmax_h(const u32* __restrict__ h2, const int* __restrict__ rowptr,
                                                  const u16* __restrict__ esrc, u32* __restrict__ agg2, int n) {
    int w = threadIdx.x >> 6, lane = threadIdx.x & 63;
    int node0 = blockIdx.x * 8 + w;
    int node1 = node0 + 4;
    seg2_body(h2, rowptr, esrc, agg2, node0, node1, lane, n);
}

// XCD-parity-split dual: blockIdx&1 selects plane; block = 8 nodes of that plane
__global__ __launch_bounds__(256) void k_segmax_h2s(const u32* __restrict__ hA, const u32* __restrict__ hB,
                                                    const int* __restrict__ rowptr, const u16* __restrict__ esrc,
                                                    u32* __restrict__ aggA, u32* __restrict__ aggB, int n) {
    int pl = blockIdx.x & 1;
    int nb = blockIdx.x >> 1;
    int w = threadIdx.x >> 6, lane = threadIdx.x & 63;
    int node0 = nb * 8 + w;
    int node1 = node0 + 4;
    seg2_body(pl ? hB : hA, rowptr, esrc, pl ? aggB : aggA, node0, node1, lane, n);
}

// ---------------- GEMM body (fp16 weights/activations, BM=128, M=32/wave) ----------------
template<int HEAD>
__device__ __forceinline__ void gemm_body(
        const u16* __restrict__ Ahi, const u16* __restrict__ Xh,
        const u16* __restrict__ Wh, const float* __restrict__ bias,
        u32* __restrict__ outh,
        const float* __restrict__ hw, const float* __restrict__ hb,
        float* __restrict__ hout, int n, int bid, u16 (*smw)[4096]) {
    int tid  = threadIdx.x;
    int wave = tid >> 6, lane = tid & 63;
    int rit  = lane & 15, kgrp = lane >> 4;
    int m0   = bid * 128 + wave * 32;
    int ar0  = m0 + rit;      if (ar0 > n - 1) ar0 = n - 1;
    int ar1  = m0 + 16 + rit; if (ar1 > n - 1) ar1 = n - 1;

    #define STAGEH(s_, b_) do {                                                  \
        _Pragma("unroll")                                                        \
        for (int q = 0; q < 2; ++q) {                                            \
            int tt = wave * 2 + q;                                               \
            const u16* g = Wh + (((tt << 3) + (s_)) << 9) + (lane << 3);         \
            gload_lds16(g, &smw[b_][tt << 9]);                                   \
        }                                                                        \
    } while (0)

    half8 a0[4], a1[4], xh0[4], xh1[4];
    #pragma unroll
    for (int s = 0; s < 4; ++s) {
        size_t o0 = (size_t)ar0 * C + s * 32 + kgrp * 8;
        size_t o1 = (size_t)ar1 * C + s * 32 + kgrp * 8;
        a0[s]  = *(const half8*)(Ahi + o0);
        a1[s]  = *(const half8*)(Ahi + o1);
        xh0[s] = *(const half8*)(Xh + o0);
        xh1[s] = *(const half8*)(Xh + o1);
    }

    f32x4 acc0[8], acc1[8];
    #pragma unroll
    for (int t = 0; t < 8; ++t) {
        acc0[t] = (f32x4){0.f, 0.f, 0.f, 0.f};
        acc1[t] = (f32x4){0.f, 0.f, 0.f, 0.f};
    }

    STAGEH(0, 0);
    __syncthreads();

    #pragma unroll
    for (int s = 0; s < 8; ++s) {
        if (s < 7) STAGEH(s + 1, (s + 1) & 1);
        const u16* base = smw[s & 1];
        half8 f0 = (s < 4) ? a0[s] : xh0[s - 4];
        half8 f1 = (s < 4) ? a1[s] : xh1[s - 4];
        #pragma unroll
        for (int t = 0; t < 8; ++t) {
            half8 wv = *(const half8*)(base + (t << 9) + (lane << 3));
            acc0[t] = __builtin_amdgcn_mfma_f32_16x16x32_f16(f0, wv, acc0[t], 0, 0, 0);
            acc1[t] = __builtin_amdgcn_mfma_f32_16x16x32_f16(f1, wv, acc1[t], 0, 0, 0);
        }
        if (s < 7) __syncthreads();
    }
    #undef STAGEH

    if (HEAD) {
        float hsA[4] = {0.f, 0.f, 0.f, 0.f}, hsB[4] = {0.f, 0.f, 0.f, 0.f};
        #pragma unroll
        for (int t = 0; t < 8; ++t) {
            int col = t * 16 + rit;
            float b = bias[col], w = hw[col];
            #pragma unroll
            for (int j = 0; j < 4; ++j) {
                hsA[j] += fmaxf(acc0[t][j] + b, 0.f) * w;
                hsB[j] += fmaxf(acc1[t][j] + b, 0.f) * w;
            }
        }
        #pragma unroll
        for (int msk = 1; msk < 16; msk <<= 1) {
            #pragma unroll
            for (int j = 0; j < 4; ++j) {
                hsA[j] += __shfl_xor(hsA[j], msk, 64);
                hsB[j] += __shfl_xor(hsB[j], msk, 64);
            }
        }
        if (rit == 0) {
            float hbv = hb[0];
            #pragma unroll
            for (int j = 0; j < 4; ++j) {
                int rA = m0 + kgrp * 4 + j;
                int rB = rA + 16;
                if (rA < n) hout[rA] = hsA[j] + hbv;
                if (rB < n) hout[rB] = hsB[j] + hbv;
            }
        }
    } else {
        #pragma unroll
        for (int g = 0; g < 2; ++g) {
            int rbase = m0 + g * 16 + kgrp * 4;
            #pragma unroll
            for (int t = 0; t < 8; ++t) {
                int col = t * 16 + rit;
                float b = bias[col];
                #pragma unroll
                for (int j = 0; j < 4; ++j) {
                    int rr = rbase + j;
                    float v = fmaxf((g ? acc1[t][j] : acc0[t][j]) + b, 0.f);
                    float pv = __shfl_xor(v, 1, 64);
                    if (!(rit & 1) && rr < n)
                        outh[(size_t)rr * 64 + (col >> 1)] = ((u32)f2h(v)) | (((u32)f2h(pv)) << 16);
                }
            }
        }
    }
}

// L1 GEMM
__global__ __launch_bounds__(256, 2) void k_gemm_p(
        const u16* __restrict__ Ahi, const u16* __restrict__ Xh,
        const u16* __restrict__ Wh, const float* __restrict__ bias, u32* __restrict__ outh, int n) {
    __shared__ __align__(16) u16 smw[2][4096];
    gemm_body<0>(Ahi, Xh, Wh, bias, outh, nullptr, nullptr, nullptr, n, blockIdx.x, smw);
}

// merged L3 GEMMs + heads: grid = 2*GT, XCD-parity branch select
__global__ __launch_bounds__(256, 2) void k_gemm_heads(
        const u16* __restrict__ AhiA, const u16* __restrict__ XhA,
        const u16* __restrict__ WhA, const float* __restrict__ biasA,
        const float* __restrict__ hwA, const float* __restrict__ hbA, float* __restrict__ houtA,
        const u16* __restrict__ AhiB, const u16* __restrict__ XhB,
        const u16* __restrict__ WhB, const float* __restrict__ biasB,
        const float* __restrict__ hwB, const float* __restrict__ hbB, float* __restrict__ houtB,
        int n) {
    __shared__ __align__(16) u16 smw[2][4096];
    int br  = blockIdx.x & 1;
    int bid = blockIdx.x >> 1;
    gemm_body<1>(br ? AhiB : AhiA, br ? XhB : XhA, br ? WhB : WhA,
                 br ? biasB : biasA, nullptr,
                 br ? hwB : hwA, br ? hbB : hbA, br ? houtB : houtA,
                 n, bid, smw);
}

// dual-output L2: two weight sets against the same (A, X)
__global__ __launch_bounds__(256, 2) void k_gemm_p2(
        const u16* __restrict__ Ahi, const u16* __restrict__ Xh,
        const u16* __restrict__ Wh1, const float* __restrict__ b1, u32* __restrict__ out1,
        const u16* __restrict__ Wh2, const float* __restrict__ b2, u32* __restrict__ out2, int n) {
    __shared__ __align__(16) u16 smw[2][8192];  // 2 sets x 8 slices x 512 u16
    int tid  = threadIdx.x;
    int wave = tid >> 6, lane = tid & 63;
    int rit  = lane & 15, kgrp = lane >> 4;
    int m0   = blockIdx.x * 128 + wave * 32;
    int ar0  = m0 + rit;      if (ar0 > n - 1) ar0 = n - 1;
    int ar1  = m0 + 16 + rit; if (ar1 > n - 1) ar1 = n - 1;

    #define STAGE2H(s_, b_) do {                                                 \
        _Pragma("unroll")                                                        \
        for (int q = 0; q < 4; ++q) {                                            \
            int kk = wave * 4 + q;                                               \
            int set = kk >> 3, tt = kk & 7;                                      \
            const u16* g = (set ? Wh2 : Wh1) + (((tt << 3) + (s_)) << 9) + (lane << 3); \
            gload_lds16(g, &smw[b_][set * 4096 + (tt << 9)]);                    \
        }                                                                        \
    } while (0)

    half8 a0[4], a1[4], xh0[4], xh1[4];
    #pragma unroll
    for (int s = 0; s < 4; ++s) {
        size_t o0 = (size_t)ar0 * C + s * 32 + kgrp * 8;
        size_t o1 = (size_t)ar1 * C + s * 32 + kgrp * 8;
        a0[s]  = *(const half8*)(Ahi + o0);
        a1[s]  = *(const half8*)(Ahi + o1);
        xh0[s] = *(const half8*)(Xh + o0);
        xh1[s] = *(const half8*)(Xh + o1);
    }

    f32x4 accA0[8], accA1[8], accB0[8], accB1[8];
    #pragma unroll
    for (int t = 0; t < 8; ++t) {
        accA0[t] = (f32x4){0.f, 0.f, 0.f, 0.f};
        accA1[t] = (f32x4){0.f, 0.f, 0.f, 0.f};
        accB0[t] = (f32x4){0.f, 0.f, 0.f, 0.f};
        accB1[t] = (f32x4){0.f, 0.f, 0.f, 0.f};
    }

    STAGE2H(0, 0);
    __syncthreads();

    #pragma unroll
    for (int s = 0; s < 8; ++s) {
        if (s < 7) STAGE2H(s + 1, (s + 1) & 1);
        const u16* base = smw[s & 1];
        half8 f0 = (s < 4) ? a0[s] : xh0[s - 4];
        half8 f1 = (s < 4) ? a1[s] : xh1[s - 4];
        #pragma unroll
        for (int t = 0; t < 8; ++t) {
            half8 wa = *(const half8*)(base + (t << 9) + (lane << 3));
            half8 wb = *(const half8*)(base + 4096 + (t << 9) + (lane << 3));
            accA0[t] = __builtin_amdgcn_mfma_f32_16x16x32_f16(f0, wa, accA0[t], 0, 0, 0);
            accA1[t] = __builtin_amdgcn_mfma_f32_16x16x32_f16(f1, wa, accA1[t], 0, 0, 0);
            accB0[t] = __builtin_amdgcn_mfma_f32_16x16x32_f16(f0, wb, accB0[t], 0, 0, 0);
            accB1[t] = __builtin_amdgcn_mfma_f32_16x16x32_f16(f1, wb, accB1[t], 0, 0, 0);
        }
        if (s < 7) __syncthreads();
    }
    #undef STAGE2H

    #pragma unroll
    for (int e = 0; e < 2; ++e) {
        const float* bb = e ? b2 : b1;
        u32* oo = e ? out2 : out1;
        #pragma unroll
        for (int g = 0; g < 2; ++g) {
            int rbase = m0 + g * 16 + kgrp * 4;
            #pragma unroll
            for (int t = 0; t < 8; ++t) {
                int col = t * 16 + rit;
                float b = bb[col];
                #pragma unroll
                for (int j = 0; j < 4; ++j) {
                    int rr = rbase + j;
                    float acv = e ? (g ? accB1[t][j] : accB0[t][j])
                                  : (g ? accA1[t][j] : accA0[t][j]);
                    float v = fmaxf(acv + b, 0.f);
                    float pv = __shfl_xor(v, 1, 64);
                    if (!(rit & 1) && rr < n)
                        oo[(size_t)rr * 64 + (col >> 1)] = ((u32)f2h(v)) | (((u32)f2h(pv)) << 16);
                }
            }
        }
    }
}

// ---------------- launch ----------------

extern "C" void kernel_launch(void* const* d_in, const int* in_sizes, int n_in,
                              void* d_out, int out_size, void* d_ws, size_t ws_size,
                              hipStream_t stream) {
    const float* x     = (const float*)d_in[0];
    const int*   ei    = (const int*)d_in[1];
    const int*   src   = ei;
    const int*   dstp  = ei + NE;
    const float* sWl   = (const float*)d_in[2];
    const float* sB    = (const float*)d_in[3];
    const float* sWr   = (const float*)d_in[4];
    const float* rt1Wl = (const float*)d_in[5];
    const float* rt1B  = (const float*)d_in[6];
    const float* rt1Wr = (const float*)d_in[7];
    const float* rt2Wl = (const float*)d_in[8];
    const float* rt2B  = (const float*)d_in[9];
    const float* rt2Wr = (const float*)d_in[10];
    const float* rt3W  = (const float*)d_in[11];
    const float* rt3B  = (const float*)d_in[12];
    const float* mv1Wl = (const float*)d_in[13];
    const float* mv1B  = (const float*)d_in[14];
    const float* mv1Wr = (const float*)d_in[15];
    const float* mv2Wl = (const float*)d_in[16];
    const float* mv2B  = (const float*)d_in[17];
    const float* mv2Wr = (const float*)d_in[18];
    const float* mv3W  = (const float*)d_in[19];
    const float* mv3B  = (const float*)d_in[20];
    float* out = (float*)d_out;

    char* ws = (char*)d_ws;
    int* rowptr  = (int*)ws;                  // NN+1
    int* deg     = rowptr + (NN + 1);         // NN
    int* bsum    = deg + NN;                  // 64
    u16* esrc16  = (u16*)(bsum + 64);         // NE u16
    size_t off   = (((size_t)(NN + 1 + NN + 64) * 4 + (size_t)NE * 2) + 255) & ~(size_t)255;
    // 5 fp16 planes, each NN*64 u32 = 12.8 MB
    u32* P[5];
    for (int i = 0; i < 5; ++i) P[i] = (u32*)(ws + off) + (size_t)i * NN * 64;
    u16* wpack = (u16*)(P[4] + (size_t)NN * 64);
    u16* pk[5];
    for (int L = 0; L < 5; ++L) pk[L] = wpack + (size_t)L * 32768;

    const int NB = (NN + 1023) / 1024;
    const int NCVT = (NN * 64 + 255) / 256;

    PackArgs pa;
    pa.Wl[0] = sWl;   pa.Wr[0] = sWr;
    pa.Wl[1] = rt1Wl; pa.Wr[1] = rt1Wr;
    pa.Wl[2] = rt2Wl; pa.Wr[2] = rt2Wr;
    pa.Wl[3] = mv1Wl; pa.Wr[3] = mv1Wr;
    pa.Wl[4] = mv2Wl; pa.Wr[4] = mv2Wr;
    for (int L = 0; L < 5; ++L) pa.Wh[L] = pk[L];

    // deg zero, then merged {hist | weight pack | x convert}
    k_zero<<<NB, 1024, 0, stream>>>(deg, NN);
    k_preph<<<GCH + 640 + NCVT, 256, 0, stream>>>(pa, x, P[0], dstp, deg, NN * 64, NE);
    k_scan_blk<<<NB, 1024, 0, stream>>>(deg, rowptr, bsum, NN);
    k_scan_add<<<NB, 1024, 0, stream>>>(rowptr, bsum, NN, NB);
    k_fill_x<<<GCH, 256, 0, stream>>>(src, dstp, rowptr, deg, esrc16, NE);

    const int GT = (NN + 127) / 128;
    const int GS8 = (NN + 7) / 8;

    // shared layer: agg(x)->P1; mv = relu(sage(x)) -> P2
    k_segmax_h<<<GS8, 256, 0, stream>>>(P[0], rowptr, esrc16, P[1], NN);
    k_gemm_p<<<GT, 256, 0, stream>>>((const u16*)P[1], (const u16*)P[0],
                                     pk[0], sB, P[2], NN);
    // agg(mv) -> P3; dual GEMM: rt -> P1, md -> P4
    k_segmax_h<<<GS8, 256, 0, stream>>>(P[2], rowptr, esrc16, P[3], NN);
    k_gemm_p2<<<GT, 256, 0, stream>>>((const u16*)P[3], (const u16*)P[2],
                                      pk[1], rt1B, P[1],
                                      pk[3], mv1B, P[4], NN);
    // XCD-parity-split dual aggregation: agg(rt) -> P0, agg(md) -> P3
    k_segmax_h2s<<<2 * GS8, 256, 0, stream>>>(
        P[1], P[4], rowptr, esrc16, P[0], P[3], NN);
    // merged L3 + heads (one dispatch, 2*GT blocks, parity branch select)
    k_gemm_heads<<<2 * GT, 256, 0, stream>>>(
        (const u16*)P[0], (const u16*)P[1], pk[2], rt2B, rt3W, rt3B, out,
        (const u16*)P[3], (const u16*)P[4], pk[4], mv2B, mv3W, mv3B, out + NN,
        NN);
}

// Round 20
// 246.812 us; speedup vs baseline: 1.0207x; 1.0207x over previous
//
#include <hip/hip_runtime.h>
#include <hip/hip_bf16.h>
#include <hip/hip_fp16.h>
#include <math.h>

#define NN 50000
#define NE 800000
#define C  128
#define NR 8            // dst ranges (XCD-affine via blockIdx%8 heuristic)
#define RNG (NN / NR)
#define GCH 1568        // ((NE+4095)/4096)*NR
typedef unsigned int u32;
typedef unsigned short u16;

using f32x4  = __attribute__((ext_vector_type(4))) float;
using half8  = __attribute__((ext_vector_type(8))) _Float16;
using half2v = __attribute__((ext_vector_type(2))) _Float16;

__device__ __forceinline__ u16 f2h(float f) {
    _Float16 h = (_Float16)f;
    return __builtin_bit_cast(u16, h);
}

__device__ __forceinline__ void gload_lds16(const u16* g, u16* l) {
    __builtin_amdgcn_global_load_lds(
        (const __attribute__((address_space(1))) u32*)g,
        (__attribute__((address_space(3))) u32*)l,
        16, 0, 0);
}

// ---------------- CSR build ----------------

__global__ __launch_bounds__(1024) void k_zero(int* __restrict__ p, int n) {
    int i = blockIdx.x * 1024 + threadIdx.x;
    if (i < n) p[i] = 0;
}

// merged: histogram (blocks 0..GCH-1) + weight pack (next 640) + x convert (rest)
struct PackArgs {
    const float* Wl[5]; const float* Wr[5];
    u16* Wh[5];
};
__global__ void k_preph(PackArgs pa, const float* __restrict__ x, u32* __restrict__ oh,
                        const int* __restrict__ dst, int* __restrict__ deg, int n64, int nE) {
    int bid = blockIdx.x;
    if (bid < GCH) {                       // range-partitioned histogram
        int r    = bid & (NR - 1);
        int base = (bid >> 3) * 4096;
        int lo   = r * RNG, hi = lo + RNG;
        #pragma unroll
        for (int it = 0; it < 16; ++it) {
            int e = base + it * 256 + threadIdx.x;
            if (e < nE) {
                int d = dst[e];
                if (d >= lo && d < hi) atomicAdd(&deg[d], 1);
            }
        }
    } else if (bid < GCH + 640) {          // weight pack (5 layers x 128 blocks)
        int b   = bid - GCH;
        int L   = b >> 7;
        int idx = (b & 127) * 256 + threadIdx.x;
        int j = idx & 7, l = (idx >> 3) & 63, s = (idx >> 9) & 7, t = idx >> 12;
        int nrow = t * 16 + (l & 15);
        int k    = s * 32 + (l >> 4) * 8 + j;
        float v  = (k < 128) ? pa.Wl[L][nrow * 128 + k] : pa.Wr[L][nrow * 128 + (k - 128)];
        pa.Wh[L][idx] = f2h(v);
    } else {                               // x conversion
        int i = (bid - GCH - 640) * 256 + threadIdx.x;
        if (i < n64) {
            float2 v = *(const float2*)(x + (size_t)i * 2);
            oh[i] = ((u32)f2h(v.x)) | (((u32)f2h(v.y)) << 16);
        }
    }
}

__global__ __launch_bounds__(1024) void k_scan_blk(const int* __restrict__ deg, int* __restrict__ rowptr,
                                                   int* __restrict__ bsum, int n) {
    __shared__ int wsum[16];
    int tid = threadIdx.x, lane = tid & 63, wid = tid >> 6;
    int i = blockIdx.x * 1024 + tid;
    int v = (i < n) ? deg[i] : 0;
    int incl = v;
    #pragma unroll
    for (int d = 1; d < 64; d <<= 1) {
        int t = __shfl_up(incl, d, 64);
        if (lane >= d) incl += t;
    }
    if (lane == 63) wsum[wid] = incl;
    __syncthreads();
    int wo = 0;
    #pragma unroll
    for (int w = 0; w < 16; ++w) wo += (w < wid) ? wsum[w] : 0;
    if (i < n) rowptr[i + 1] = wo + incl;
    if (tid == 1023) bsum[blockIdx.x] = wo + incl;
}

// scan bsum in-register per block (nb <= 49 < 64), then add offsets
__global__ __launch_bounds__(1024) void k_scan_add(int* __restrict__ rowptr, const int* __restrict__ bsum,
                                                   int n, int nb) {
    __shared__ int soff;
    int tid = threadIdx.x;
    if (tid < 64) {
        int v = (tid < nb) ? bsum[tid] : 0;
        int incl = v;
        #pragma unroll
        for (int d = 1; d < 64; d <<= 1) {
            int t = __shfl_up(incl, d, 64);
            if (tid >= d) incl += t;
        }
        if (tid == blockIdx.x) soff = incl - v;   // exclusive prefix for this block
    }
    __syncthreads();
    int i = blockIdx.x * 1024 + tid;
    if (i == 0) rowptr[0] = 0;
    if (i < n) rowptr[i + 1] += soff;
}

__global__ __launch_bounds__(256) void k_fill_x(const int* __restrict__ src, const int* __restrict__ dst,
                                                const int* __restrict__ rowptr, int* __restrict__ deg,
                                                u16* __restrict__ esrc, int nE) {
    int r    = blockIdx.x & (NR - 1);
    int base = (blockIdx.x >> 3) * 4096;
    int lo   = r * RNG, hi = lo + RNG;
    #pragma unroll
    for (int it = 0; it < 16; ++it) {
        int e = base + it * 256 + threadIdx.x;
        if (e < nE) {
            int d = dst[e];
            if (d >= lo && d < hi) {
                int old = atomicSub(&deg[d], 1);
                esrc[rowptr[d + 1] - old] = (u16)src[e];
            }
        }
    }
}

// ---------------- segment max over packed fp16 (v_pk_max_f16) ----------------
// beg/end forced to SGPR via readfirstlane: the whole edge-index chain becomes
// wave-uniform -> esrc loads scalarize (SMEM), freeing VALU/VMEM issue slots
// for the gathers. node is wave-uniform by construction, so this is exact.

// single plane: 16 clamped edge slots in flight per wave; packed max, no unpack
__global__ __launch_bounds__(256) void k_segmax_h(const u32* __restrict__ h2, const int* __restrict__ rowptr,
                                                  const u16* __restrict__ esrc, u32* __restrict__ agg2, int n) {
    int node = blockIdx.x * 4 + (threadIdx.x >> 6);
    int lane = threadIdx.x & 63;
    if (node >= n) return;
    int beg = __builtin_amdgcn_readfirstlane(rowptr[node]);
    int end = __builtin_amdgcn_readfirstlane(rowptr[node + 1]);
    _Float16 ninf = (_Float16)(-INFINITY);
    half2v m = {ninf, ninf};
    int last = end - 1;
    for (int i = beg; i < end; i += 16) {
        u32 w[16];
        #pragma unroll
        for (int q = 0; q < 16; ++q) {
            int e = i + q; if (e > last) e = last;
            w[q] = h2[((size_t)esrc[e] << 6) + lane];
        }
        #pragma unroll
        for (int q = 0; q < 16; ++q)
            m = __builtin_elementwise_max(m, __builtin_bit_cast(half2v, w[q]));
    }
    u32 r = (end > beg) ? __builtin_bit_cast(u32, m) : 0u;
    __builtin_nontemporal_store(r, &agg2[(size_t)node * 64 + lane]);
}

// XCD-parity-split dual: blockIdx.x&1 selects plane -> each XCD gathers ONE plane
__global__ __launch_bounds__(256) void k_segmax_h2s(const u32* __restrict__ hA, const u32* __restrict__ hB,
                                                    const int* __restrict__ rowptr, const u16* __restrict__ esrc,
                                                    u32* __restrict__ aggA, u32* __restrict__ aggB, int n) {
    int pl   = blockIdx.x & 1;
    int node = (blockIdx.x >> 1) * 4 + (threadIdx.x >> 6);
    int lane = threadIdx.x & 63;
    if (node >= n) return;
    const u32* h2 = pl ? hB : hA;
    u32* agg2     = pl ? aggB : aggA;
    int beg = __builtin_amdgcn_readfirstlane(rowptr[node]);
    int end = __builtin_amdgcn_readfirstlane(rowptr[node + 1]);
    _Float16 ninf = (_Float16)(-INFINITY);
    half2v m = {ninf, ninf};
    int last = end - 1;
    for (int i = beg; i < end; i += 16) {
        u32 w[16];
        #pragma unroll
        for (int q = 0; q < 16; ++q) {
            int e = i + q; if (e > last) e = last;
            w[q] = h2[((size_t)esrc[e] << 6) + lane];
        }
        #pragma unroll
        for (int q = 0; q < 16; ++q)
            m = __builtin_elementwise_max(m, __builtin_bit_cast(half2v, w[q]));
    }
    u32 r = (end > beg) ? __builtin_bit_cast(u32, m) : 0u;
    __builtin_nontemporal_store(r, &agg2[(size_t)node * 64 + lane]);
}

// ---------------- GEMM body (fp16 weights/activations, BM=128, M=32/wave) ----------------
template<int HEAD>
__device__ __forceinline__ void gemm_body(
        const u16* __restrict__ Ahi, const u16* __restrict__ Xh,
        const u16* __restrict__ Wh, const float* __restrict__ bias,
        u32* __restrict__ outh,
        const float* __restrict__ hw, const float* __restrict__ hb,
        float* __restrict__ hout, int n, int bid, u16 (*smw)[4096]) {
    int tid  = threadIdx.x;
    int wave = tid >> 6, lane = tid & 63;
    int rit  = lane & 15, kgrp = lane >> 4;
    int m0   = bid * 128 + wave * 32;
    int ar0  = m0 + rit;      if (ar0 > n - 1) ar0 = n - 1;
    int ar1  = m0 + 16 + rit; if (ar1 > n - 1) ar1 = n - 1;

    #define STAGEH(s_, b_) do {                                                  \
        _Pragma("unroll")                                                        \
        for (int q = 0; q < 2; ++q) {                                            \
            int tt = wave * 2 + q;                                               \
            const u16* g = Wh + (((tt << 3) + (s_)) << 9) + (lane << 3);         \
            gload_lds16(g, &smw[b_][tt << 9]);                                   \
        }                                                                        \
    } while (0)

    half8 a0[4], a1[4], xh0[4], xh1[4];
    #pragma unroll
    for (int s = 0; s < 4; ++s) {
        size_t o0 = (size_t)ar0 * C + s * 32 + kgrp * 8;
        size_t o1 = (size_t)ar1 * C + s * 32 + kgrp * 8;
        a0[s]  = *(const half8*)(Ahi + o0);
        a1[s]  = *(const half8*)(Ahi + o1);
        xh0[s] = *(const half8*)(Xh + o0);
        xh1[s] = *(const half8*)(Xh + o1);
    }

    f32x4 acc0[8], acc1[8];
    #pragma unroll
    for (int t = 0; t < 8; ++t) {
        acc0[t] = (f32x4){0.f, 0.f, 0.f, 0.f};
        acc1[t] = (f32x4){0.f, 0.f, 0.f, 0.f};
    }

    STAGEH(0, 0);
    __syncthreads();

    #pragma unroll
    for (int s = 0; s < 8; ++s) {
        if (s < 7) STAGEH(s + 1, (s + 1) & 1);
        const u16* base = smw[s & 1];
        half8 f0 = (s < 4) ? a0[s] : xh0[s - 4];
        half8 f1 = (s < 4) ? a1[s] : xh1[s - 4];
        #pragma unroll
        for (int t = 0; t < 8; ++t) {
            half8 wv = *(const half8*)(base + (t << 9) + (lane << 3));
            acc0[t] = __builtin_amdgcn_mfma_f32_16x16x32_f16(f0, wv, acc0[t], 0, 0, 0);
            acc1[t] = __builtin_amdgcn_mfma_f32_16x16x32_f16(f1, wv, acc1[t], 0, 0, 0);
        }
        if (s < 7) __syncthreads();
    }
    #undef STAGEH

    if (HEAD) {
        float hsA[4] = {0.f, 0.f, 0.f, 0.f}, hsB[4] = {0.f, 0.f, 0.f, 0.f};
        #pragma unroll
        for (int t = 0; t < 8; ++t) {
            int col = t * 16 + rit;
            float b = bias[col], w = hw[col];
            #pragma unroll
            for (int j = 0; j < 4; ++j) {
                hsA[j] += fmaxf(acc0[t][j] + b, 0.f) * w;
                hsB[j] += fmaxf(acc1[t][j] + b, 0.f) * w;
            }
        }
        #pragma unroll
        for (int msk = 1; msk < 16; msk <<= 1) {
            #pragma unroll
            for (int j = 0; j < 4; ++j) {
                hsA[j] += __shfl_xor(hsA[j], msk, 64);
                hsB[j] += __shfl_xor(hsB[j], msk, 64);
            }
        }
        if (rit == 0) {
            float hbv = hb[0];
            #pragma unroll
            for (int j = 0; j < 4; ++j) {
                int rA = m0 + kgrp * 4 + j;
                int rB = rA + 16;
                if (rA < n) hout[rA] = hsA[j] + hbv;
                if (rB < n) hout[rB] = hsB[j] + hbv;
            }
        }
    } else {
        #pragma unroll
        for (int g = 0; g < 2; ++g) {
            int rbase = m0 + g * 16 + kgrp * 4;
            #pragma unroll
            for (int t = 0; t < 8; ++t) {
                int col = t * 16 + rit;
                float b = bias[col];
                #pragma unroll
                for (int j = 0; j < 4; ++j) {
                    int rr = rbase + j;
                    float v = fmaxf((g ? acc1[t][j] : acc0[t][j]) + b, 0.f);
                    float pv = __shfl_xor(v, 1, 64);
                    if (!(rit & 1) && rr < n)
                        outh[(size_t)rr * 64 + (col >> 1)] = ((u32)f2h(v)) | (((u32)f2h(pv)) << 16);
                }
            }
        }
    }
}

// L1 GEMM
__global__ __launch_bounds__(256, 2) void k_gemm_p(
        const u16* __restrict__ Ahi, const u16* __restrict__ Xh,
        const u16* __restrict__ Wh, const float* __restrict__ bias, u32* __restrict__ outh, int n) {
    __shared__ __align__(16) u16 smw[2][4096];
    gemm_body<0>(Ahi, Xh, Wh, bias, outh, nullptr, nullptr, nullptr, n, blockIdx.x, smw);
}

// merged L3 GEMMs + heads: grid = 2*GT, XCD-parity branch select
__global__ __launch_bounds__(256, 2) void k_gemm_heads(
        const u16* __restrict__ AhiA, const u16* __restrict__ XhA,
        const u16* __restrict__ WhA, const float* __restrict__ biasA,
        const float* __restrict__ hwA, const float* __restrict__ hbA, float* __restrict__ houtA,
        const u16* __restrict__ AhiB, const u16* __restrict__ XhB,
        const u16* __restrict__ WhB, const float* __restrict__ biasB,
        const float* __restrict__ hwB, const float* __restrict__ hbB, float* __restrict__ houtB,
        int n) {
    __shared__ __align__(16) u16 smw[2][4096];
    int br  = blockIdx.x & 1;
    int bid = blockIdx.x >> 1;
    gemm_body<1>(br ? AhiB : AhiA, br ? XhB : XhA, br ? WhB : WhA,
                 br ? biasB : biasA, nullptr,
                 br ? hwB : hwA, br ? hbB : hbA, br ? houtB : houtA,
                 n, bid, smw);
}

// dual-output L2: two weight sets against the same (A, X)
__global__ __launch_bounds__(256, 2) void k_gemm_p2(
        const u16* __restrict__ Ahi, const u16* __restrict__ Xh,
        const u16* __restrict__ Wh1, const float* __restrict__ b1, u32* __restrict__ out1,
        const u16* __restrict__ Wh2, const float* __restrict__ b2, u32* __restrict__ out2, int n) {
    __shared__ __align__(16) u16 smw[2][8192];  // 2 sets x 8 slices x 512 u16
    int tid  = threadIdx.x;
    int wave = tid >> 6, lane = tid & 63;
    int rit  = lane & 15, kgrp = lane >> 4;
    int m0   = blockIdx.x * 128 + wave * 32;
    int ar0  = m0 + rit;      if (ar0 > n - 1) ar0 = n - 1;
    int ar1  = m0 + 16 + rit; if (ar1 > n - 1) ar1 = n - 1;

    #define STAGE2H(s_, b_) do {                                                 \
        _Pragma("unroll")                                                        \
        for (int q = 0; q < 4; ++q) {                                            \
            int kk = wave * 4 + q;                                               \
            int set = kk >> 3, tt = kk & 7;                                      \
            const u16* g = (set ? Wh2 : Wh1) + (((tt << 3) + (s_)) << 9) + (lane << 3); \
            gload_lds16(g, &smw[b_][set * 4096 + (tt << 9)]);                    \
        }                                                                        \
    } while (0)

    half8 a0[4], a1[4], xh0[4], xh1[4];
    #pragma unroll
    for (int s = 0; s < 4; ++s) {
        size_t o0 = (size_t)ar0 * C + s * 32 + kgrp * 8;
        size_t o1 = (size_t)ar1 * C + s * 32 + kgrp * 8;
        a0[s]  = *(const half8*)(Ahi + o0);
        a1[s]  = *(const half8*)(Ahi + o1);
        xh0[s] = *(const half8*)(Xh + o0);
        xh1[s] = *(const half8*)(Xh + o1);
    }

    f32x4 accA0[8], accA1[8], accB0[8], accB1[8];
    #pragma unroll
    for (int t = 0; t < 8; ++t) {
        accA0[t] = (f32x4){0.f, 0.f, 0.f, 0.f};
        accA1[t] = (f32x4){0.f, 0.f, 0.f, 0.f};
        accB0[t] = (f32x4){0.f, 0.f, 0.f, 0.f};
        accB1[t] = (f32x4){0.f, 0.f, 0.f, 0.f};
    }

    STAGE2H(0, 0);
    __syncthreads();

    #pragma unroll
    for (int s = 0; s < 8; ++s) {
        if (s < 7) STAGE2H(s + 1, (s + 1) & 1);
        const u16* base = smw[s & 1];
        half8 f0 = (s < 4) ? a0[s] : xh0[s - 4];
        half8 f1 = (s < 4) ? a1[s] : xh1[s - 4];
        #pragma unroll
        for (int t = 0; t < 8; ++t) {
            half8 wa = *(const half8*)(base + (t << 9) + (lane << 3));
            half8 wb = *(const half8*)(base + 4096 + (t << 9) + (lane << 3));
            accA0[t] = __builtin_amdgcn_mfma_f32_16x16x32_f16(f0, wa, accA0[t], 0, 0, 0);
            accA1[t] = __builtin_amdgcn_mfma_f32_16x16x32_f16(f1, wa, accA1[t], 0, 0, 0);
            accB0[t] = __builtin_amdgcn_mfma_f32_16x16x32_f16(f0, wb, accB0[t], 0, 0, 0);
            accB1[t] = __builtin_amdgcn_mfma_f32_16x16x32_f16(f1, wb, accB1[t], 0, 0, 0);
        }
        if (s < 7) __syncthreads();
    }
    #undef STAGE2H

    #pragma unroll
    for (int e = 0; e < 2; ++e) {
        const float* bb = e ? b2 : b1;
        u32* oo = e ? out2 : out1;
        #pragma unroll
        for (int g = 0; g < 2; ++g) {
            int rbase = m0 + g * 16 + kgrp * 4;
            #pragma unroll
            for (int t = 0; t < 8; ++t) {
                int col = t * 16 + rit;
                float b = bb[col];
                #pragma unroll
                for (int j = 0; j < 4; ++j) {
                    int rr = rbase + j;
                    float acv = e ? (g ? accB1[t][j] : accB0[t][j])
                                  : (g ? accA1[t][j] : accA0[t][j]);
                    float v = fmaxf(acv + b, 0.f);
                    float pv = __shfl_xor(v, 1, 64);
                    if (!(rit & 1) && rr < n)
                        oo[(size_t)rr * 64 + (col >> 1)] = ((u32)f2h(v)) | (((u32)f2h(pv)) << 16);
                }
            }
        }
    }
}

// ---------------- launch ----------------

extern "C" void kernel_launch(void* const* d_in, const int* in_sizes, int n_in,
                              void* d_out, int out_size, void* d_ws, size_t ws_size,
                              hipStream_t stream) {
    const float* x     = (const float*)d_in[0];
    const int*   ei    = (const int*)d_in[1];
    const int*   src   = ei;
    const int*   dstp  = ei + NE;
    const float* sWl   = (const float*)d_in[2];
    const float* sB    = (const float*)d_in[3];
    const float* sWr   = (const float*)d_in[4];
    const float* rt1Wl = (const float*)d_in[5];
    const float* rt1B  = (const float*)d_in[6];
    const float* rt1Wr = (const float*)d_in[7];
    const float* rt2Wl = (const float*)d_in[8];
    const float* rt2B  = (const float*)d_in[9];
    const float* rt2Wr = (const float*)d_in[10];
    const float* rt3W  = (const float*)d_in[11];
    const float* rt3B  = (const float*)d_in[12];
    const float* mv1Wl = (const float*)d_in[13];
    const float* mv1B  = (const float*)d_in[14];
    const float* mv1Wr = (const float*)d_in[15];
    const float* mv2Wl = (const float*)d_in[16];
    const float* mv2B  = (const float*)d_in[17];
    const float* mv2Wr = (const float*)d_in[18];
    const float* mv3W  = (const float*)d_in[19];
    const float* mv3B  = (const float*)d_in[20];
    float* out = (float*)d_out;

    char* ws = (char*)d_ws;
    int* rowptr  = (int*)ws;                  // NN+1
    int* deg     = rowptr + (NN + 1);         // NN
    int* bsum    = deg + NN;                  // 64
    u16* esrc16  = (u16*)(bsum + 64);         // NE u16
    size_t off   = (((size_t)(NN + 1 + NN + 64) * 4 + (size_t)NE * 2) + 255) & ~(size_t)255;
    // 5 fp16 planes, each NN*64 u32 = 12.8 MB
    u32* P[5];
    for (int i = 0; i < 5; ++i) P[i] = (u32*)(ws + off) + (size_t)i * NN * 64;
    u16* wpack = (u16*)(P[4] + (size_t)NN * 64);
    u16* pk[5];
    for (int L = 0; L < 5; ++L) pk[L] = wpack + (size_t)L * 32768;

    const int NB = (NN + 1023) / 1024;
    const int NCVT = (NN * 64 + 255) / 256;

    PackArgs pa;
    pa.Wl[0] = sWl;   pa.Wr[0] = sWr;
    pa.Wl[1] = rt1Wl; pa.Wr[1] = rt1Wr;
    pa.Wl[2] = rt2Wl; pa.Wr[2] = rt2Wr;
    pa.Wl[3] = mv1Wl; pa.Wr[3] = mv1Wr;
    pa.Wl[4] = mv2Wl; pa.Wr[4] = mv2Wr;
    for (int L = 0; L < 5; ++L) pa.Wh[L] = pk[L];

    // deg zero, then merged {hist | weight pack | x convert}
    k_zero<<<NB, 1024, 0, stream>>>(deg, NN);
    k_preph<<<GCH + 640 + NCVT, 256, 0, stream>>>(pa, x, P[0], dstp, deg, NN * 64, NE);
    k_scan_blk<<<NB, 1024, 0, stream>>>(deg, rowptr, bsum, NN);
    k_scan_add<<<NB, 1024, 0, stream>>>(rowptr, bsum, NN, NB);
    k_fill_x<<<GCH, 256, 0, stream>>>(src, dstp, rowptr, deg, esrc16, NE);

    dim3 gSeg((NN + 3) / 4), bSeg(256);
    const int GT = (NN + 127) / 128;

    // shared layer: agg(x)->P1; mv = relu(sage(x)) -> P2
    k_segmax_h<<<gSeg, bSeg, 0, stream>>>(P[0], rowptr, esrc16, P[1], NN);
    k_gemm_p<<<GT, 256, 0, stream>>>((const u16*)P[1], (const u16*)P[0],
                                     pk[0], sB, P[2], NN);
    // agg(mv) -> P3; dual GEMM: rt -> P1, md -> P4
    k_segmax_h<<<gSeg, bSeg, 0, stream>>>(P[2], rowptr, esrc16, P[3], NN);
    k_gemm_p2<<<GT, 256, 0, stream>>>((const u16*)P[3], (const u16*)P[2],
                                      pk[1], rt1B, P[1],
                                      pk[3], mv1B, P[4], NN);
    // XCD-parity-split dual aggregation: agg(rt) -> P0, agg(md) -> P3
    k_segmax_h2s<<<dim3(2 * ((NN + 3) / 4)), bSeg, 0, stream>>>(
        P[1], P[4], rowptr, esrc16, P[0], P[3], NN);
    // merged L3 + heads (one dispatch, 2*GT blocks, parity branch select)
    k_gemm_heads<<<2 * GT, 256, 0, stream>>>(
        (const u16*)P[0], (const u16*)P[1], pk[2], rt2B, rt3W, rt3B, out,
        (const u16*)P[3], (const u16*)P[4], pk[4], mv2B, mv3W, mv3B, out + NN,
        NN);
}